// Round 8
// baseline (234.925 us; speedup 1.0000x reference)
//
#include <hip/hip_runtime.h>

#define Rn 64
#define Hn 10
#define Fn 5

typedef float f32x2 __attribute__((ext_vector_type(2)));

__device__ __forceinline__ float fsigmoid(float x) {
    return __builtin_amdgcn_rcpf(1.0f + __expf(-x));
}
__device__ __forceinline__ float ftanh(float x) {
    return 1.0f - 2.0f * __builtin_amdgcn_rcpf(__expf(2.0f * x) + 1.0f);
}

// Round-4 structure (proven: 2 lanes/batch via shfl_xor(32), weights in LDS,
// double-buffered x tiles, 1 barrier per 4 steps) + packed-f32 math:
// gate/r-gate inner loops use v_pk_fma_f32 (__builtin_elementwise_fma on
// float2) and weight reads become 8B ds_read_b64 broadcasts (halves both the
// VALU FMA issue count and the LDS instruction count).
__global__ __launch_bounds__(256, 2) void seqreader_kernel(
    const float* __restrict__ r_emb,
    const float* __restrict__ feature,
    const float* __restrict__ h0,
    const float* __restrict__ c0,
    const float* __restrict__ W_ih,
    const float* __restrict__ W_hh,
    const float* __restrict__ b_ih,
    const float* __restrict__ b_hh,
    const float* __restrict__ Wr,
    const float* __restrict__ br,
    const float* __restrict__ Wh,
    const float* __restrict__ bh,
    const float* __restrict__ Wfc,
    const float* __restrict__ bfc,
    float* __restrict__ out)
{
    __shared__ __align__(16) float sWih[40 * 12];
    __shared__ __align__(16) float sWhh[40 * 12];
    __shared__ __align__(16) float sWr[10 * 12];
    __shared__ __align__(16) float sWhn[10 * 12];
    __shared__ float sWfc[646];
    __shared__ float sX[2][128 * 41];  // [buf][batch][40 + pad]

    const int tid  = threadIdx.x;
    const int lane = tid & 63;
    const int half = lane >> 5;        // 0: rows 0-4, 1: rows 5-9
    const int r0h  = half * 5;
    const int bb   = (tid >> 6) * 32 + (lane & 31);  // batch within block, 0..127
    const int b0   = blockIdx.x * 128;
    const int b    = b0 + bb;

    // stage weights (padded row stride 12 -> even col pairs are 8B-aligned)
    for (int i = tid; i < 400; i += 256) {
        int r = i / 10, k = i - r * 10;
        sWih[r * 12 + k] = W_ih[i];
        sWhh[r * 12 + k] = W_hh[i];
    }
    for (int i = tid; i < 100; i += 256) {
        int r = i / 10, k = i - r * 10;
        sWr[r * 12 + k]  = Wr[i];
        sWhn[r * 12 + k] = Wh[i];
    }
    for (int i = tid; i < 645; i += 256) sWfc[i] = Wfc[i];

    // per-lane-half biases (loaded once into VGPRs)
    float bi[5], bf_[5], bg_[5], bo[5], brh[5];
#pragma unroll
    for (int j = 0; j < 5; ++j) {
        bi[j]  = b_ih[0  + r0h + j] + b_hh[0  + r0h + j];
        bf_[j] = b_ih[10 + r0h + j] + b_hh[10 + r0h + j];
        bg_[j] = b_ih[20 + r0h + j] + b_hh[20 + r0h + j];
        bo[j]  = b_ih[30 + r0h + j] + b_hh[30 + r0h + j];
        brh[j] = br[r0h + j] + bh[r0h + j];
    }

    float c[5];
#pragma unroll
    for (int j = 0; j < 5; ++j) c[j] = c0[b * Hn + r0h + j];
    float hf[Hn];
#pragma unroll
    for (int k = 0; k < Hn; ++k) hf[k] = h0[b * Hn + k];

    float acc = 0.0f;
    if (half == 0) {
        acc = bfc[0];
#pragma unroll
        for (int k = 0; k < Fn; ++k)
            acc = fmaf(feature[b * Fn + k], Wfc[Rn * Hn + k], acc);
    }

    // gather map: tile = 128 batches x 40 floats = 1280 float4; 5 per thread
    unsigned off_g[5], off_l[5];
#pragma unroll
    for (int k = 0; k < 5; ++k) {
        int q  = k * 256 + tid;
        int bq = q / 10;
        int e  = q - bq * 10;
        off_g[k] = (unsigned)((bq * (Rn * Hn) + e * 4) * 4);  // bytes
        off_l[k] = (unsigned)(bq * 41 + e * 4);               // dwords
    }
    const char* gb = (const char*)(r_emb + (size_t)b0 * (Rn * Hn));

    // stage tile 0
    {
        float4 s0[5];
#pragma unroll
        for (int k = 0; k < 5; ++k) s0[k] = *(const float4*)(gb + off_g[k]);
#pragma unroll
        for (int k = 0; k < 5; ++k) {
            float* d = &sX[0][off_l[k]];
            d[0] = s0[k].x; d[1] = s0[k].y; d[2] = s0[k].z; d[3] = s0[k].w;
        }
    }
    __syncthreads();

    float4 st[5];
#pragma unroll 1
    for (int t = 0; t < Rn; ++t) {
        const int tt = t & 3;
        const int Tb = (t >> 2) & 1;

        if (tt == 0 && t + 4 < Rn) {
#pragma unroll
            for (int k = 0; k < 5; ++k)
                st[k] = *(const float4*)(gb + off_g[k] + (unsigned)(t / 4 + 1) * 160u);
        }

        float x[Hn];
        const float* xr = &sX[Tb][bb * 41 + tt * Hn];
#pragma unroll
        for (int j = 0; j < Hn; ++j) x[j] = xr[j];

        // packed operand pairs for this step
        f32x2 x2[5], h2[5];
#pragma unroll
        for (int p = 0; p < 5; ++p) {
            x2[p] = f32x2{x[2 * p], x[2 * p + 1]};
            h2[p] = f32x2{hf[2 * p], hf[2 * p + 1]};
        }

        // own half of the LSTM cell (5 rows, all 4 gates) -- packed FMAs
        float hn[5];
#pragma unroll
        for (int j = 0; j < 5; ++j) {
            f32x2 si2 = {bi[j],  0.f};
            f32x2 sf2 = {bf_[j], 0.f};
            f32x2 sg2 = {bg_[j], 0.f};
            f32x2 so2 = {bo[j],  0.f};
            const int ri = (0  + r0h + j) * 12;
            const int rf = (10 + r0h + j) * 12;
            const int rg = (20 + r0h + j) * 12;
            const int ro = (30 + r0h + j) * 12;
#pragma unroll
            for (int p = 0; p < 5; ++p) {
                const f32x2 xp = x2[p], hp = h2[p];
                si2 = __builtin_elementwise_fma(*(const f32x2*)&sWih[ri + 2 * p], xp, si2);
                si2 = __builtin_elementwise_fma(*(const f32x2*)&sWhh[ri + 2 * p], hp, si2);
                sf2 = __builtin_elementwise_fma(*(const f32x2*)&sWih[rf + 2 * p], xp, sf2);
                sf2 = __builtin_elementwise_fma(*(const f32x2*)&sWhh[rf + 2 * p], hp, sf2);
                sg2 = __builtin_elementwise_fma(*(const f32x2*)&sWih[rg + 2 * p], xp, sg2);
                sg2 = __builtin_elementwise_fma(*(const f32x2*)&sWhh[rg + 2 * p], hp, sg2);
                so2 = __builtin_elementwise_fma(*(const f32x2*)&sWih[ro + 2 * p], xp, so2);
                so2 = __builtin_elementwise_fma(*(const f32x2*)&sWhh[ro + 2 * p], hp, so2);
            }
            const float si = si2[0] + si2[1];
            const float sf = sf2[0] + sf2[1];
            const float sg = sg2[0] + sg2[1];
            const float so = so2[0] + so2[1];
            const float cn = fsigmoid(sf) * c[j] + fsigmoid(si) * ftanh(sg);
            c[j] = cn;
            hn[j] = fsigmoid(so) * ftanh(cn);
        }

        // exchange halves in-wave: partner lane = lane ^ 32
        float sw[5];
#pragma unroll
        for (int j = 0; j < 5; ++j) sw[j] = __shfl_xor(hn[j], 32, 64);
#pragma unroll
        for (int j = 0; j < 5; ++j) {
            hf[j]     = half ? sw[j] : hn[j];
            hf[5 + j] = half ? hn[j] : sw[j];
        }

        // write next x tile into the other buffer (prefetched at tt==0)
        if (tt == 2 && t + 2 < Rn) {
#pragma unroll
            for (int k = 0; k < 5; ++k) {
                float* d = &sX[Tb ^ 1][off_l[k]];
                d[0] = st[k].x; d[1] = st[k].y; d[2] = st[k].z; d[3] = st[k].w;
            }
        }

        // r-gate + fused FC accumulation (own rows) -- packed FMAs
        f32x2 hn2[5];
#pragma unroll
        for (int p = 0; p < 5; ++p) hn2[p] = f32x2{hf[2 * p], hf[2 * p + 1]};
#pragma unroll
        for (int j = 0; j < 5; ++j) {
            f32x2 s2 = {brh[j], 0.f};
            const int rr = (r0h + j) * 12;
#pragma unroll
            for (int p = 0; p < 5; ++p) {
                s2 = __builtin_elementwise_fma(*(const f32x2*)&sWr[rr + 2 * p],  x2[p],  s2);
                s2 = __builtin_elementwise_fma(*(const f32x2*)&sWhn[rr + 2 * p], hn2[p], s2);
            }
            const float s = s2[0] + s2[1];
            acc = fmaf(hn[j] * fsigmoid(s), sWfc[t * Hn + r0h + j], acc);
        }

        if (tt == 3) __syncthreads();
    }

    // combine the two lane-halves' partial FC sums; half 0 writes
    acc += __shfl_xor(acc, 32, 64);
    if (half == 0) out[b] = acc;
}

extern "C" void kernel_launch(void* const* d_in, const int* in_sizes, int n_in,
                              void* d_out, int out_size, void* d_ws, size_t ws_size,
                              hipStream_t stream) {
    const float* r_emb   = (const float*)d_in[0];
    const float* feature = (const float*)d_in[1];
    const float* h0      = (const float*)d_in[2];
    const float* c0      = (const float*)d_in[3];
    const float* W_ih    = (const float*)d_in[4];
    const float* W_hh    = (const float*)d_in[5];
    const float* b_ih    = (const float*)d_in[6];
    const float* b_hh    = (const float*)d_in[7];
    const float* Wr      = (const float*)d_in[8];
    const float* br      = (const float*)d_in[9];
    const float* Wh      = (const float*)d_in[10];
    const float* bh      = (const float*)d_in[11];
    const float* Wfc     = (const float*)d_in[12];
    const float* bfc     = (const float*)d_in[13];
    float* out = (float*)d_out;

    dim3 grid(65536 / 128), block(256);
    hipLaunchKernelGGL(seqreader_kernel, grid, block, 0, stream,
                       r_emb, feature, h0, c0, W_ih, W_hh, b_ih, b_hh,
                       Wr, br, Wh, bh, Wfc, bfc, out);
}